// Round 13
// baseline (691.743 us; speedup 1.0000x reference)
//
#include <hip/hip_runtime.h>
#include <math.h>

#define D_MODEL 1536
#define NH      8
#define HD      192
#define BB      16
#define LL      64
#define UU      64
#define NTOK    1024
#define EPSF    1e-5f

typedef __bf16 bf16;
typedef __bf16 bf16x4_t __attribute__((ext_vector_type(4)));
typedef __bf16 bf16x8_t __attribute__((ext_vector_type(8)));
typedef float  f32x4_t  __attribute__((ext_vector_type(4)));

__device__ __forceinline__ void gload_lds16(const bf16* g, bf16* l) {
    __builtin_amdgcn_global_load_lds((const __attribute__((address_space(1))) void*)g,
                                     (__attribute__((address_space(3))) void*)l, 16, 0, 0);
}

// ------- merged prep: blocks [0,1024) fused pooling; [1024,3072) weight cvt --
__global__ __launch_bounds__(256)
void prep_kernel(const float* __restrict__ x, const float* __restrict__ pw,
                 const float* __restrict__ pb, const float* __restrict__ pos,
                 float* __restrict__ h, bf16* __restrict__ hb,
                 bf16* __restrict__ memb,
                 const float* __restrict__ s0, const float* __restrict__ s1,
                 const float* __restrict__ s2, const float* __restrict__ s3,
                 const float* __restrict__ s4, const float* __restrict__ s5,
                 bf16* __restrict__ dst)
{
    const int t = threadIdx.x;
    if (blockIdx.x >= 1024) {
        const int c0 = 3538944, c1 = 4718592, c2 = 8257536,
                  c3 = 9437184, c4 = 11010048, c5 = 12582912;   // float4 bounds
        for (int i = (blockIdx.x - 1024) * 256 + t; i < c5; i += 2048 * 256) {
            const float* s; int j;
            if      (i < c0) { s = s0; j = i; }
            else if (i < c1) { s = s1; j = i - c0; }
            else if (i < c2) { s = s2; j = i - c1; }
            else if (i < c3) { s = s3; j = i - c2; }
            else if (i < c4) { s = s4; j = i - c3; }
            else             { s = s5; j = i - c4; }
            const float4 v = ((const float4*)s)[j];
            bf16x4_t o = { (bf16)v.x, (bf16)v.y, (bf16)v.z, (bf16)v.w };
            ((bf16x4_t*)dst)[i] = o;
        }
        return;
    }
    __shared__ float red[2][4];
    const int wave = t >> 6, lane = t & 63;
    const int bl = blockIdx.x, l = bl & (LL - 1);
    const float* xb = x + (size_t)bl * UU * D_MODEL;

    float pwr[6];
#pragma unroll
    for (int j = 0; j < 6; ++j) pwr[j] = pw[t + j * 256];
    const float pb0 = pb[0];

    float xv[2][6];
#pragma unroll
    for (int j = 0; j < 6; ++j) xv[0][j] = xb[t + j * 256];

    float m = -__builtin_inff(), den = 0.f;
    float acc[6] = {0.f, 0.f, 0.f, 0.f, 0.f, 0.f};

    for (int u = 0; u < UU; ++u) {
        const int cur = u & 1;
        if (u < UU - 1) {
            const float* xn = xb + (size_t)(u + 1) * D_MODEL;
#pragma unroll
            for (int j = 0; j < 6; ++j) xv[cur ^ 1][j] = xn[t + j * 256];
        }
        float p = 0.f;
#pragma unroll
        for (int j = 0; j < 6; ++j) p += xv[cur][j] * pwr[j];
#pragma unroll
        for (int off = 32; off; off >>= 1) p += __shfl_xor(p, off, 64);
        if (lane == 0) red[cur][wave] = p;
        __syncthreads();
        const float logit = red[cur][0] + red[cur][1] + red[cur][2] + red[cur][3] + pb0;
        const float nm = fmaxf(m, logit);
        const float sc = __expf(m - nm);
        const float w  = __expf(logit - nm);
#pragma unroll
        for (int j = 0; j < 6; ++j) acc[j] = acc[j] * sc + w * xv[cur][j];
        den = den * sc + w;
        m = nm;
    }

    const float inv = 1.f / den;
    const size_t db = (size_t)bl * D_MODEL;
    const int pp = l * D_MODEL;
#pragma unroll
    for (int j = 0; j < 6; ++j) {
        const int d = t + j * 256;
        const float v = acc[j] * inv + pos[pp + d];
        h[db + d] = v;
        hb[db + d] = (bf16)v;
        memb[db + d] = (bf16)v;
    }
}

// ---------------- bf16 GEMM, 8-wave 128x128 tile, counted-vmcnt dbuf ------
// C = A(M=1024,K) @ W(N,K)^T + bias.  BM=128, BN=128, BK=64.
// 8 waves as 2m x 4n; each wave 64x32 (acc[4][2]); 32 MFMA/wave/K-tile.
// Staging: 4 gload_lds/wave/tile (2 A-chunks + 2 B-chunks of 8 rows each);
// chunk c covers rows c*8+lr so row&7==lr -> swizzle invariant preserved.
// MODE 0: fp32 out (partials if SPLITK); 1: relu+bf16; 2: bf16 out.
// SPLITK in {0,2,4}; DUAL: vid>=split -> problem 2.
template<int MODE, bool DUAL, int SPLITK>
__global__ __launch_bounds__(512, 4)
void gemm8_kernel(const bf16* __restrict__ A, const bf16* __restrict__ W,
                  const float* __restrict__ bias, void* __restrict__ Cv,
                  int N, int K, int split,
                  const bf16* __restrict__ A2, const bf16* __restrict__ W2,
                  const float* __restrict__ bias2, void* __restrict__ Cv2, int N2)
{
    __shared__ bf16 As[2][128 * 64];
    __shared__ bf16 Bs[2][128 * 64];
    const int t = threadIdx.x, wave = t >> 6, lane = t & 63;

    // XCD-chunked bijective swizzle (all grids multiple of 8)
    const int T = gridDim.x, fid = blockIdx.x;
    int vid = (fid & 7) * (T >> 3) + (fid >> 3);
    const bf16* Ap = A; const bf16* Wp = W; const float* bp = bias;
    void* Cp = Cv; int Nn = N;
    if (DUAL && vid >= split) { vid -= split; Ap = A2; Wp = W2; bp = bias2; Cp = Cv2; Nn = N2; }
    int kslice = 0;
    if (SPLITK == 2) { kslice = vid & 1; vid >>= 1; }
    else if (SPLITK == 4) { kslice = vid & 3; vid >>= 2; }
    const int m0 = (vid & 7) * 128;        // M/BM == 8 (M=1024)
    const int n0 = (vid >> 3) * 128;
    const int Kl = SPLITK ? K / SPLITK : K;
    const int kbase = kslice * Kl;

    const int wm = wave >> 2, wn = wave & 3;     // 2m x 4n waves, each 64x32
    const int frow = lane & 15, kq = lane >> 4, s = frow & 7;
    const int lr = lane >> 3;
    const int g8 = ((lane & 7) ^ lr) * 8;        // pre-swizzled source granule

    f32x4_t acc[4][2] = {};

    // wave stages A rows wave*16+{0,8}+lr and B rows wave*16+{0,8}+lr
    const bf16* Abase = Ap + (size_t)(m0 + wave * 16 + lr) * K + kbase + g8;
    const bf16* Wbase = Wp + (size_t)(n0 + wave * 16 + lr) * K + kbase + g8;

    auto STAGE = [&](int buf, int tile) {
        const int k0 = tile << 6;
        gload_lds16(Abase + k0,                 &As[buf][wave * 1024]);
        gload_lds16(Abase + k0 + (size_t)8 * K, &As[buf][wave * 1024 + 512]);
        gload_lds16(Wbase + k0,                 &Bs[buf][wave * 1024]);
        gload_lds16(Wbase + k0 + (size_t)8 * K, &Bs[buf][wave * 1024 + 512]);
    };
    auto COMPUTE = [&](int buf) {
#pragma unroll
        for (int kk = 0; kk < 2; ++kk) {
            const int gg = (((kk << 2) | kq) ^ s) * 8;
            bf16x8_t af[4], bv[2];
#pragma unroll
            for (int mi = 0; mi < 4; ++mi)
                af[mi] = *(const bf16x8_t*)&As[buf][(wm * 64 + mi * 16 + frow) * 64 + gg];
#pragma unroll
            for (int ni = 0; ni < 2; ++ni)
                bv[ni] = *(const bf16x8_t*)&Bs[buf][(wn * 32 + ni * 16 + frow) * 64 + gg];
#pragma unroll
            for (int mi = 0; mi < 4; ++mi)
#pragma unroll
                for (int ni = 0; ni < 2; ++ni)
                    acc[mi][ni] = __builtin_amdgcn_mfma_f32_16x16x32_bf16(af[mi], bv[ni], acc[mi][ni], 0, 0, 0);
        }
    };

    const int nt = Kl >> 6;                 // >= 6 for all dispatches
    STAGE(0, 0);
    STAGE(1, 1);
    for (int tt = 0; tt + 1 < nt; ++tt) {
        // wait own oldest 4 (tile tt); barrier => ALL waves' tile tt landed
        asm volatile("s_waitcnt vmcnt(4)" ::: "memory");
        __builtin_amdgcn_s_barrier();
        COMPUTE(tt & 1);
        __builtin_amdgcn_s_barrier();
        if (tt + 2 < nt) STAGE(tt & 1, tt + 2);
    }
    asm volatile("s_waitcnt vmcnt(0)" ::: "memory");
    __builtin_amdgcn_s_barrier();
    COMPUTE((nt - 1) & 1);

    float* Cpart = (float*)Cp + (SPLITK ? (size_t)kslice * NTOK * Nn : 0);
    const int crow = m0 + wm * 64 + kq * 4;
    const int ccol = n0 + wn * 32 + frow;
#pragma unroll
    for (int mi = 0; mi < 4; ++mi)
#pragma unroll
        for (int ni = 0; ni < 2; ++ni) {
            const int col = ccol + ni * 16;
            const float bvv = (SPLITK && kslice) ? 0.f : bp[col];
            const int rb = crow + mi * 16;
#pragma unroll
            for (int j = 0; j < 4; ++j) {
                float v = acc[mi][ni][j] + bvv;
                if (MODE == 0) {
                    Cpart[(size_t)(rb + j) * Nn + col] = v;
                } else if (MODE == 1) {
                    ((bf16*)Cp)[(size_t)(rb + j) * Nn + col] = (bf16)fmaxf(v, 0.f);
                } else {
                    ((bf16*)Cp)[(size_t)(rb + j) * Nn + col] = (bf16)v;
                }
            }
        }
}

// ---------------- split-K reduce + relu -> bf16 (for ff1, 2 partials) -----
__global__ __launch_bounds__(256)
void reduce_relu_kernel(const float* __restrict__ p0, const float* __restrict__ p1,
                        bf16* __restrict__ dst, int n4)
{
    const int i = blockIdx.x * 256 + threadIdx.x;
    if (i >= n4) return;
    const float4 a = ((const float4*)p0)[i];
    const float4 b = ((const float4*)p1)[i];
    bf16x4_t o = { (bf16)fmaxf(a.x + b.x, 0.f), (bf16)fmaxf(a.y + b.y, 0.f),
                   (bf16)fmaxf(a.z + b.z, 0.f), (bf16)fmaxf(a.w + b.w, 0.f) };
    ((bf16x4_t*)dst)[i] = o;
}

// ---------------- fp32-core attention, bf16 K/V, 4 q-chunks per (b,h) -----
// Q4: q = sum of 4 fp32 split-K partials (stride PN); else q is bf16.
template<bool CAUSAL, bool Q4>
__global__ __launch_bounds__(256)
void attn_kernel(const bf16* __restrict__ qb, const float* __restrict__ qp, int PN,
                 int qstride, int qoff0,
                 const bf16* __restrict__ kbuf, int kstride, int koff0,
                 const bf16* __restrict__ vbuf, int vstride, int voff0,
                 bf16* __restrict__ out)
{
    __shared__ float kv[HD * 64];    // K phase: K^T swizzled [d][k]; V phase: [k][d]
    __shared__ float sc[16 * 64];    // this chunk's P rows
    const int t = threadIdx.x, wave = t >> 6, lane = t & 63;
    const int bh = blockIdx.x >> 2, qh = blockIdx.x & 3;
    const int b = bh >> 3, hh = bh & 7;
    const int t0 = b * 64;
    const float scale = rsqrtf((float)HD);

    for (int i = 0; i < 48; ++i) {
        const int idx = t + i * 256;
        const int r = idx / HD, c = idx % HD;
        kv[c * 64 + (r ^ (c & 31))] =
            (float)kbuf[(size_t)(t0 + r) * kstride + koff0 + hh * HD + c];
    }
    __syncthreads();

    for (int qi = 0; qi < 4; ++qi) {
        const int ql = wave * 4 + qi;
        const int q = qh * 16 + ql;
        const size_t qb0 = (size_t)(t0 + q) * qstride + qoff0 + hh * HD;
        float a = 0.f;
#pragma unroll 8
        for (int d = 0; d < HD; ++d) {
            float qv;
            if (Q4) qv = qp[qb0 + d] + qp[(size_t)PN + qb0 + d]
                       + qp[2 * (size_t)PN + qb0 + d] + qp[3 * (size_t)PN + qb0 + d];
            else    qv = (float)qb[qb0 + d];
            a += qv * kv[d * 64 + (lane ^ (d & 31))];
        }
        a *= scale;
        if (CAUSAL && lane > q) a = -__builtin_inff();
        float m = a;
#pragma unroll
        for (int off = 32; off; off >>= 1) m = fmaxf(m, __shfl_xor(m, off, 64));
        float e = (CAUSAL && lane > q) ? 0.f : __expf(a - m);
        float s = e;
#pragma unroll
        for (int off = 32; off; off >>= 1) s += __shfl_xor(s, off, 64);
        sc[ql * 64 + lane] = e / s;
    }
    __syncthreads();

    for (int i = 0; i < 48; ++i) {
        const int idx = t + i * 256;
        const int r = idx / HD, c = idx % HD;
        kv[r * HD + c] = (float)vbuf[(size_t)(t0 + r) * vstride + voff0 + hh * HD + c];
    }
    __syncthreads();

    for (int qi = 0; qi < 4; ++qi) {
        const int ql = wave * 4 + qi;
        const int q = qh * 16 + ql;
        float o0 = 0.f, o1 = 0.f, o2 = 0.f;
#pragma unroll 8
        for (int k = 0; k < 64; ++k) {
            const float p = sc[ql * 64 + k];
            o0 += p * kv[k * HD + lane];
            o1 += p * kv[k * HD + 64 + lane];
            o2 += p * kv[k * HD + 128 + lane];
        }
        bf16* op = out + (size_t)(t0 + q) * D_MODEL + hh * HD;
        op[lane] = (bf16)o0; op[64 + lane] = (bf16)o1; op[128 + lane] = (bf16)o2;
    }
}

// ------- residual + LayerNorm, 4 split-K partials, optional slice-out -----
template<bool SLICE>
__global__ __launch_bounds__(256)
void ln_kernel(const float* __restrict__ a, const float* __restrict__ p, int PN,
               const float* __restrict__ w, const float* __restrict__ bb,
               float* __restrict__ out, bf16* __restrict__ outb,
               float* __restrict__ out2)
{
    __shared__ float red[8];
    const int tok = blockIdx.x, t = threadIdx.x;
    const int wave = t >> 6, lane = t & 63;
    const float* ap = a + (size_t)tok * D_MODEL;
    const float* pp = p + (size_t)tok * D_MODEL;
    float v[6];
    float s = 0.f;
#pragma unroll
    for (int j = 0; j < 6; ++j) {
        const int d = t + j * 256;
        v[j] = ap[d] + pp[d] + pp[(size_t)PN + d]
             + pp[2 * (size_t)PN + d] + pp[3 * (size_t)PN + d];
        s += v[j];
    }
#pragma unroll
    for (int off = 32; off; off >>= 1) s += __shfl_xor(s, off, 64);
    if (lane == 0) red[wave] = s;
    __syncthreads();
    const float mu = (red[0] + red[1] + red[2] + red[3]) * (1.f / D_MODEL);
    float s2 = 0.f;
#pragma unroll
    for (int j = 0; j < 6; ++j) { const float d = v[j] - mu; s2 += d * d; }
#pragma unroll
    for (int off = 32; off; off >>= 1) s2 += __shfl_xor(s2, off, 64);
    if (lane == 0) red[4 + wave] = s2;
    __syncthreads();
    const float var = (red[4] + red[5] + red[6] + red[7]) * (1.f / D_MODEL);
    const float inv = rsqrtf(var + EPSF);
    const int bq = tok >> 6, lq = tok & 63;
#pragma unroll
    for (int j = 0; j < 6; ++j) {
        const int d = t + j * 256;
        const float o = (v[j] - mu) * inv * w[d] + bb[d];
        out[(size_t)tok * D_MODEL + d] = o;
        outb[(size_t)tok * D_MODEL + d] = (bf16)o;
        if (SLICE && lq < 63) out2[(size_t)(bq * 63 + lq) * D_MODEL + d] = o;
    }
}

extern "C" void kernel_launch(void* const* d_in, const int* in_sizes, int n_in,
                              void* d_out, int out_size, void* d_ws, size_t ws_size,
                              hipStream_t stream)
{
    (void)in_sizes; (void)n_in; (void)out_size; (void)ws_size;
    const float* x        = (const float*)d_in[0];
    const float* pooler_w = (const float*)d_in[1];
    const float* pooler_b = (const float*)d_in[2];
    const float* pos      = (const float*)d_in[3];
    const float* sa_qkv_w = (const float*)d_in[4];
    const float* sa_qkv_b = (const float*)d_in[5];
    const float* sa_out_w = (const float*)d_in[6];
    const float* sa_out_b = (const float*)d_in[7];
    const float* ca_qkv_w = (const float*)d_in[8];
    const float* ca_qkv_b = (const float*)d_in[9];
    const float* ca_out_w = (const float*)d_in[10];
    const float* ca_out_b = (const float*)d_in[11];
    const float* ff1_w    = (const float*)d_in[12];
    const float* ff1_b    = (const float*)d_in[13];
    const float* ff2_w    = (const float*)d_in[14];
    const float* ff2_b    = (const float*)d_in[15];
    const float* ln1_w    = (const float*)d_in[16];
    const float* ln1_b    = (const float*)d_in[17];
    const float* ln2_w    = (const float*)d_in[18];
    const float* ln2_b    = (const float*)d_in[19];
    const float* ln3_w    = (const float*)d_in[20];
    const float* ln3_b    = (const float*)d_in[21];
    float* outp = (float*)d_out;

    char* ws = (char*)d_ws;
    size_t off = 0;
    auto alloc = [&](size_t bytes) { char* p = ws + off; off += (bytes + 255) & ~(size_t)255; return p; };

    const size_t E_QKV = (size_t)4608 * D_MODEL;
    const size_t E_SQ  = (size_t)D_MODEL * D_MODEL;
    const size_t E_F1  = (size_t)2048 * D_MODEL;
    const int    PN    = NTOK * D_MODEL;           // partial stride (elems)

    // contiguous bf16 weight block (order must match prep cvt boundaries)
    bf16* wb_sa_qkv = (bf16*)alloc(2 * E_QKV * 2);
    bf16* wb_sa_out = (bf16*)alloc(2 * E_SQ * 2);
    bf16* wb_ca_qkv = (bf16*)alloc(2 * E_QKV * 2);
    bf16* wb_ca_out = (bf16*)alloc(2 * E_SQ * 2);
    bf16* wb_ff1    = (bf16*)alloc(2 * E_F1 * 2);
    bf16* wb_ff2    = (bf16*)alloc(2 * E_F1 * 2);
    float* h     = (float*)alloc((size_t)NTOK * D_MODEL * 4);
    bf16*  hb    = (bf16*) alloc((size_t)NTOK * D_MODEL * 2);
    bf16*  memb  = (bf16*) alloc((size_t)NTOK * D_MODEL * 2);
    bf16*  qkvb  = (bf16*) alloc((size_t)NTOK * 4608 * 2);
    float* cq4   = (float*)alloc((size_t)PN * 4 * 4);               // 4 partials
    bf16*  ckv0  = (bf16*) alloc((size_t)NTOK * 3072 * 2);
    bf16*  ckv1  = (bf16*) alloc((size_t)NTOK * 3072 * 2);
    bf16*  attno = (bf16*) alloc((size_t)NTOK * D_MODEL * 2);
    float* proj4 = (float*)alloc((size_t)PN * 4 * 4);               // 4 partials
    float* f1p01 = (float*)alloc((size_t)NTOK * 2048 * 4 * 2);      // 2 partials
    bf16*  ffmid = (bf16*) alloc((size_t)NTOK * 2048 * 2);

    float* f1p1 = f1p01 + (size_t)NTOK * 2048;

    prep_kernel<<<3072, 256, 0, stream>>>(x, pooler_w, pooler_b, pos, h, hb, memb,
                                          sa_qkv_w, sa_out_w, ca_qkv_w,
                                          ca_out_w, ff1_w, ff2_w, wb_sa_qkv);

    // both layers' cross-attn K/V depend only on memb: one DUAL bf16 dispatch
    gemm8_kernel<2, true, 0><<<8 * 24 * 2, 512, 0, stream>>>(
        memb, wb_ca_qkv + (size_t)1536 * D_MODEL, ca_qkv_b + 1536,
        ckv0, 3072, D_MODEL, 8 * 24,
        memb, wb_ca_qkv + E_QKV + (size_t)1536 * D_MODEL, ca_qkv_b + 4608 + 1536,
        ckv1, 3072);

    for (int i = 0; i < 2; ++i) {
        bf16* ckv = i ? ckv1 : ckv0;

        gemm8_kernel<2, false, 0><<<8 * 36, 512, 0, stream>>>(
            hb, wb_sa_qkv + (size_t)i * E_QKV, sa_qkv_b + (size_t)i * 4608,
            qkvb, 4608, D_MODEL, 0, nullptr, nullptr, nullptr, nullptr, 0);
        attn_kernel<true, false><<<BB * NH * 4, 256, 0, stream>>>(
            qkvb, nullptr, 0, 4608, 0, qkvb, 4608, 1536, qkvb, 4608, 3072, attno);
        gemm8_kernel<0, false, 4><<<8 * 12 * 4, 512, 0, stream>>>(
            attno, wb_sa_out + (size_t)i * E_SQ, sa_out_b + (size_t)i * D_MODEL,
            proj4, D_MODEL, D_MODEL, 0, nullptr, nullptr, nullptr, nullptr, 0);
        ln_kernel<false><<<NTOK, 256, 0, stream>>>(
            h, proj4, PN, ln1_w + i * D_MODEL, ln1_b + i * D_MODEL, h, hb, nullptr);

        gemm8_kernel<0, false, 4><<<8 * 12 * 4, 512, 0, stream>>>(
            hb, wb_ca_qkv + (size_t)i * E_QKV, ca_qkv_b + (size_t)i * 4608,
            cq4, D_MODEL, D_MODEL, 0, nullptr, nullptr, nullptr, nullptr, 0);
        attn_kernel<false, true><<<BB * NH * 4, 256, 0, stream>>>(
            nullptr, cq4, PN, 1536, 0, ckv, 3072, 0, ckv, 3072, 1536, attno);
        gemm8_kernel<0, false, 4><<<8 * 12 * 4, 512, 0, stream>>>(
            attno, wb_ca_out + (size_t)i * E_SQ, ca_out_b + (size_t)i * D_MODEL,
            proj4, D_MODEL, D_MODEL, 0, nullptr, nullptr, nullptr, nullptr, 0);
        ln_kernel<false><<<NTOK, 256, 0, stream>>>(
            h, proj4, PN, ln2_w + i * D_MODEL, ln2_b + i * D_MODEL, h, hb, nullptr);

        gemm8_kernel<0, false, 2><<<8 * 16 * 2, 512, 0, stream>>>(
            hb, wb_ff1 + (size_t)i * E_F1, ff1_b + (size_t)i * 2048,
            f1p01, 2048, D_MODEL, 0, nullptr, nullptr, nullptr, nullptr, 0);
        reduce_relu_kernel<<<2048, 256, 0, stream>>>(
            f1p01, f1p1, ffmid, NTOK * 2048 / 4);
        gemm8_kernel<0, false, 4><<<8 * 12 * 4, 512, 0, stream>>>(
            ffmid, wb_ff2 + (size_t)i * E_F1, ff2_b + (size_t)i * D_MODEL,
            proj4, D_MODEL, 2048, 0, nullptr, nullptr, nullptr, nullptr, 0);
        if (i == 0)
            ln_kernel<false><<<NTOK, 256, 0, stream>>>(
                h, proj4, PN, ln3_w, ln3_b, h, hb, nullptr);
        else
            ln_kernel<true><<<NTOK, 256, 0, stream>>>(
                h, proj4, PN, ln3_w + D_MODEL, ln3_b + D_MODEL, h, hb, outp);
    }
}

// Round 14
// 676.492 us; speedup vs baseline: 1.0225x; 1.0225x over previous
//
#include <hip/hip_runtime.h>
#include <math.h>

#define D_MODEL 1536
#define NH      8
#define HD      192
#define BB      16
#define LL      64
#define UU      64
#define NTOK    1024
#define EPSF    1e-5f

typedef __bf16 bf16;
typedef __bf16 bf16x4_t __attribute__((ext_vector_type(4)));
typedef __bf16 bf16x8_t __attribute__((ext_vector_type(8)));
typedef float  f32x4_t  __attribute__((ext_vector_type(4)));

__device__ __forceinline__ void gload_lds16(const bf16* g, bf16* l) {
    __builtin_amdgcn_global_load_lds((const __attribute__((address_space(1))) void*)g,
                                     (__attribute__((address_space(3))) void*)l, 16, 0, 0);
}

// ------- merged prep: blocks [0,1024) fused pooling; [1024,3072) weight cvt --
__global__ __launch_bounds__(256)
void prep_kernel(const float* __restrict__ x, const float* __restrict__ pw,
                 const float* __restrict__ pb, const float* __restrict__ pos,
                 float* __restrict__ h, bf16* __restrict__ hb,
                 bf16* __restrict__ memb,
                 const float* __restrict__ s0, const float* __restrict__ s1,
                 const float* __restrict__ s2, const float* __restrict__ s3,
                 const float* __restrict__ s4, const float* __restrict__ s5,
                 bf16* __restrict__ dst)
{
    const int t = threadIdx.x;
    if (blockIdx.x >= 1024) {
        const int c0 = 3538944, c1 = 4718592, c2 = 8257536,
                  c3 = 9437184, c4 = 11010048, c5 = 12582912;   // float4 bounds
        for (int i = (blockIdx.x - 1024) * 256 + t; i < c5; i += 2048 * 256) {
            const float* s; int j;
            if      (i < c0) { s = s0; j = i; }
            else if (i < c1) { s = s1; j = i - c0; }
            else if (i < c2) { s = s2; j = i - c1; }
            else if (i < c3) { s = s3; j = i - c2; }
            else if (i < c4) { s = s4; j = i - c3; }
            else             { s = s5; j = i - c4; }
            const float4 v = ((const float4*)s)[j];
            bf16x4_t o = { (bf16)v.x, (bf16)v.y, (bf16)v.z, (bf16)v.w };
            ((bf16x4_t*)dst)[i] = o;
        }
        return;
    }
    __shared__ float red[2][4];
    const int wave = t >> 6, lane = t & 63;
    const int bl = blockIdx.x, l = bl & (LL - 1);
    const float* xb = x + (size_t)bl * UU * D_MODEL;

    float pwr[6];
#pragma unroll
    for (int j = 0; j < 6; ++j) pwr[j] = pw[t + j * 256];
    const float pb0 = pb[0];

    float xv[2][6];
#pragma unroll
    for (int j = 0; j < 6; ++j) xv[0][j] = xb[t + j * 256];

    float m = -__builtin_inff(), den = 0.f;
    float acc[6] = {0.f, 0.f, 0.f, 0.f, 0.f, 0.f};

    for (int u = 0; u < UU; ++u) {
        const int cur = u & 1;
        if (u < UU - 1) {
            const float* xn = xb + (size_t)(u + 1) * D_MODEL;
#pragma unroll
            for (int j = 0; j < 6; ++j) xv[cur ^ 1][j] = xn[t + j * 256];
        }
        float p = 0.f;
#pragma unroll
        for (int j = 0; j < 6; ++j) p += xv[cur][j] * pwr[j];
#pragma unroll
        for (int off = 32; off; off >>= 1) p += __shfl_xor(p, off, 64);
        if (lane == 0) red[cur][wave] = p;
        __syncthreads();
        const float logit = red[cur][0] + red[cur][1] + red[cur][2] + red[cur][3] + pb0;
        const float nm = fmaxf(m, logit);
        const float sc = __expf(m - nm);
        const float w  = __expf(logit - nm);
#pragma unroll
        for (int j = 0; j < 6; ++j) acc[j] = acc[j] * sc + w * xv[cur][j];
        den = den * sc + w;
        m = nm;
    }

    const float inv = 1.f / den;
    const size_t db = (size_t)bl * D_MODEL;
    const int pp = l * D_MODEL;
#pragma unroll
    for (int j = 0; j < 6; ++j) {
        const int d = t + j * 256;
        const float v = acc[j] * inv + pos[pp + d];
        h[db + d] = v;
        hb[db + d] = (bf16)v;
        memb[db + d] = (bf16)v;
    }
}

// ---------------- bf16 GEMM, 8-wave 64x128, counted-vmcnt dbuf (r11) ------
// C = A(M=1024,K) @ W(N,K)^T + bias.  BM=64, BN=128, BK=64.
// 8 waves 2m x 4n, each 32x32 (acc[2][2]).  (512,6): 3 blocks/CU.
// MODE 0: fp32 out (partials if SPLITK); 1: relu+bf16; 2: bf16 out.
// SPLITK in {0,2}; DUAL: vid>=split -> problem 2.
template<int MODE, bool DUAL, int SPLITK>
__global__ __launch_bounds__(512, 6)
void gemm8_kernel(const bf16* __restrict__ A, const bf16* __restrict__ W,
                  const float* __restrict__ bias, void* __restrict__ Cv,
                  int N, int K, int split,
                  const bf16* __restrict__ A2, const bf16* __restrict__ W2,
                  const float* __restrict__ bias2, void* __restrict__ Cv2, int N2)
{
    __shared__ bf16 As[2][64 * 64];
    __shared__ bf16 Bs[2][128 * 64];
    const int t = threadIdx.x, wave = t >> 6, lane = t & 63;

    const int T = gridDim.x, fid = blockIdx.x;
    int vid = (fid & 7) * (T >> 3) + (fid >> 3);
    const bf16* Ap = A; const bf16* Wp = W; const float* bp = bias;
    void* Cp = Cv; int Nn = N;
    if (DUAL && vid >= split) { vid -= split; Ap = A2; Wp = W2; bp = bias2; Cp = Cv2; Nn = N2; }
    int kslice = 0;
    if (SPLITK == 2) { kslice = vid & 1; vid >>= 1; }
    const int m0 = (vid & 15) * 64;        // M/BM == 16 (M=1024)
    const int n0 = (vid >> 4) * 128;
    const int Kl = SPLITK ? K / SPLITK : K;
    const int kbase = kslice * Kl;

    const int wm = wave >> 2, wn = wave & 3;     // 2m x 4n waves, each 32x32
    const int frow = lane & 15, kq = lane >> 4, s = frow & 7;
    const int lr = lane >> 3;
    const int g8 = ((lane & 7) ^ lr) * 8;        // pre-swizzled source granule

    f32x4_t acc[2][2] = {};

    const bf16* Abase = Ap + (size_t)(m0 + wave * 8 + lr) * K + kbase + g8;
    const bf16* Wbase = Wp + (size_t)(n0 + wave * 8 + lr) * K + kbase + g8;

    auto STAGE = [&](int buf, int tile) {
        const int k0 = tile << 6;
        gload_lds16(Abase + k0, &As[buf][wave * 512]);
        gload_lds16(Wbase + k0, &Bs[buf][wave * 512]);
        gload_lds16(Wbase + k0 + (size_t)64 * K, &Bs[buf][4096 + wave * 512]);
    };
    auto COMPUTE = [&](int buf) {
#pragma unroll
        for (int kk = 0; kk < 2; ++kk) {
            const int gg = (((kk << 2) | kq) ^ s) * 8;
            bf16x8_t af[2], bv[2];
#pragma unroll
            for (int mi = 0; mi < 2; ++mi)
                af[mi] = *(const bf16x8_t*)&As[buf][(wm * 32 + mi * 16 + frow) * 64 + gg];
#pragma unroll
            for (int ni = 0; ni < 2; ++ni)
                bv[ni] = *(const bf16x8_t*)&Bs[buf][(wn * 32 + ni * 16 + frow) * 64 + gg];
#pragma unroll
            for (int mi = 0; mi < 2; ++mi)
#pragma unroll
                for (int ni = 0; ni < 2; ++ni)
                    acc[mi][ni] = __builtin_amdgcn_mfma_f32_16x16x32_bf16(af[mi], bv[ni], acc[mi][ni], 0, 0, 0);
        }
    };

    const int nt = Kl >> 6;                 // >= 12
    STAGE(0, 0);
    STAGE(1, 1);
    for (int tt = 0; tt + 1 < nt; ++tt) {
        asm volatile("s_waitcnt vmcnt(3)" ::: "memory");
        __builtin_amdgcn_s_barrier();
        COMPUTE(tt & 1);
        __builtin_amdgcn_s_barrier();
        if (tt + 2 < nt) STAGE(tt & 1, tt + 2);
    }
    asm volatile("s_waitcnt vmcnt(0)" ::: "memory");
    __builtin_amdgcn_s_barrier();
    COMPUTE((nt - 1) & 1);

    float* Cpart = (float*)Cp + (SPLITK ? (size_t)kslice * NTOK * Nn : 0);
    const int crow = m0 + wm * 32 + kq * 4;
    const int ccol = n0 + wn * 32 + frow;
#pragma unroll
    for (int mi = 0; mi < 2; ++mi)
#pragma unroll
        for (int ni = 0; ni < 2; ++ni) {
            const int col = ccol + ni * 16;
            const float bvv = (SPLITK && kslice) ? 0.f : bp[col];
            const int rb = crow + mi * 16;
#pragma unroll
            for (int j = 0; j < 4; ++j) {
                float v = acc[mi][ni][j] + bvv;
                if (MODE == 0) {
                    Cpart[(size_t)(rb + j) * Nn + col] = v;
                } else if (MODE == 1) {
                    ((bf16*)Cp)[(size_t)(rb + j) * Nn + col] = (bf16)fmaxf(v, 0.f);
                } else {
                    ((bf16*)Cp)[(size_t)(rb + j) * Nn + col] = (bf16)v;
                }
            }
        }
}

// -------- ff2 GEMM with fused split-K reduce+relu A-staging ---------------
// A(row,k) = relu(p0[row*2048+k] + p1[row*2048+k]) cast to bf16, reg-staged
// into the SAME swizzled LDS layout (thread writes granule g8 of its row).
// W path unchanged (gload_lds).  SPLITK=2 over K=2048; fp32 partials out.
__global__ __launch_bounds__(512, 4)
void gemm_ff2_kernel(const float* __restrict__ p0, const float* __restrict__ p1,
                     const float* __restrict__ bias, float* __restrict__ C,
                     const bf16* __restrict__ W, int N, int K)
{
    __shared__ bf16 As[2][64 * 64];
    __shared__ bf16 Bs[2][128 * 64];
    const int t = threadIdx.x, wave = t >> 6, lane = t & 63;

    const int T = gridDim.x, fid = blockIdx.x;
    int vid = (fid & 7) * (T >> 3) + (fid >> 3);
    const int kslice = vid & 1; vid >>= 1;
    const int m0 = (vid & 15) * 64;
    const int n0 = (vid >> 4) * 128;
    const int Kl = K >> 1;
    const int kbase = kslice * Kl;

    const int wm = wave >> 2, wn = wave & 3;
    const int frow = lane & 15, kq = lane >> 4, s = frow & 7;
    const int lr = lane >> 3;
    const int g8 = ((lane & 7) ^ lr) * 8;

    f32x4_t acc[2][2] = {};

    const int arow = m0 + wave * 8 + lr;
    const float* P0 = p0 + (size_t)arow * K + kbase + g8;
    const float* P1 = p1 + (size_t)arow * K + kbase + g8;
    const bf16* Wbase = W + (size_t)(n0 + wave * 8 + lr) * K + kbase + g8;

    auto STAGE = [&](int buf, int tile) {
        const int k0 = tile << 6;
        // A: fused add+relu+cvt, reg-staged (partials are L2-resident)
        const f32x4_t a0 = *(const f32x4_t*)(P0 + k0);
        const f32x4_t a1 = *(const f32x4_t*)(P0 + k0 + 4);
        const f32x4_t b0 = *(const f32x4_t*)(P1 + k0);
        const f32x4_t b1 = *(const f32x4_t*)(P1 + k0 + 4);
        bf16x8_t av;
#pragma unroll
        for (int j = 0; j < 4; ++j) {
            av[j]     = (bf16)fmaxf(a0[j] + b0[j], 0.f);
            av[4 + j] = (bf16)fmaxf(a1[j] + b1[j], 0.f);
        }
        *(bf16x8_t*)&As[buf][wave * 512 + lane * 8] = av;
        gload_lds16(Wbase + k0, &Bs[buf][wave * 512]);
        gload_lds16(Wbase + k0 + (size_t)64 * K, &Bs[buf][4096 + wave * 512]);
    };
    auto COMPUTE = [&](int buf) {
#pragma unroll
        for (int kk = 0; kk < 2; ++kk) {
            const int gg = (((kk << 2) | kq) ^ s) * 8;
            bf16x8_t af[2], bv[2];
#pragma unroll
            for (int mi = 0; mi < 2; ++mi)
                af[mi] = *(const bf16x8_t*)&As[buf][(wm * 32 + mi * 16 + frow) * 64 + gg];
#pragma unroll
            for (int ni = 0; ni < 2; ++ni)
                bv[ni] = *(const bf16x8_t*)&Bs[buf][(wn * 32 + ni * 16 + frow) * 64 + gg];
#pragma unroll
            for (int mi = 0; mi < 2; ++mi)
#pragma unroll
                for (int ni = 0; ni < 2; ++ni)
                    acc[mi][ni] = __builtin_amdgcn_mfma_f32_16x16x32_bf16(af[mi], bv[ni], acc[mi][ni], 0, 0, 0);
        }
    };

    const int nt = Kl >> 6;                 // 16
    STAGE(0, 0);
    STAGE(1, 1);
    for (int tt = 0; tt + 1 < nt; ++tt) {
        // wait tile tt's 2 W-gloads (A was ds_written sync in STAGE) and own
        // ds_write retire; barrier publishes both to all waves.
        asm volatile("s_waitcnt vmcnt(2) lgkmcnt(0)" ::: "memory");
        __builtin_amdgcn_s_barrier();
        COMPUTE(tt & 1);
        __builtin_amdgcn_s_barrier();
        if (tt + 2 < nt) STAGE(tt & 1, tt + 2);
    }
    asm volatile("s_waitcnt vmcnt(0) lgkmcnt(0)" ::: "memory");
    __builtin_amdgcn_s_barrier();
    COMPUTE((nt - 1) & 1);

    float* Cpart = C + (size_t)kslice * NTOK * N;
    const int crow = m0 + wm * 32 + kq * 4;
    const int ccol = n0 + wn * 32 + frow;
#pragma unroll
    for (int mi = 0; mi < 2; ++mi)
#pragma unroll
        for (int ni = 0; ni < 2; ++ni) {
            const int col = ccol + ni * 16;
            const float bvv = kslice ? 0.f : bias[col];
            const int rb = crow + mi * 16;
#pragma unroll
            for (int j = 0; j < 4; ++j)
                Cpart[(size_t)(rb + j) * N + col] = acc[mi][ni][j] + bvv;
        }
}

// ---------------- fp32-core attention, bf16 K/V, 4 q-chunks per (b,h) -----
// Q2: q = sum of 2 fp32 split-K partials (stride PN); else q is bf16.
template<bool CAUSAL, bool Q2>
__global__ __launch_bounds__(256)
void attn_kernel(const bf16* __restrict__ qb, const float* __restrict__ qp, int PN,
                 int qstride, int qoff0,
                 const bf16* __restrict__ kbuf, int kstride, int koff0,
                 const bf16* __restrict__ vbuf, int vstride, int voff0,
                 bf16* __restrict__ out)
{
    __shared__ float kv[HD * 64];
    __shared__ float sc[16 * 64];
    const int t = threadIdx.x, wave = t >> 6, lane = t & 63;
    const int bh = blockIdx.x >> 2, qh = blockIdx.x & 3;
    const int b = bh >> 3, hh = bh & 7;
    const int t0 = b * 64;
    const float scale = rsqrtf((float)HD);

    for (int i = 0; i < 48; ++i) {
        const int idx = t + i * 256;
        const int r = idx / HD, c = idx % HD;
        kv[c * 64 + (r ^ (c & 31))] =
            (float)kbuf[(size_t)(t0 + r) * kstride + koff0 + hh * HD + c];
    }
    __syncthreads();

    for (int qi = 0; qi < 4; ++qi) {
        const int ql = wave * 4 + qi;
        const int q = qh * 16 + ql;
        const size_t qb0 = (size_t)(t0 + q) * qstride + qoff0 + hh * HD;
        float a = 0.f;
#pragma unroll 8
        for (int d = 0; d < HD; ++d) {
            float qv;
            if (Q2) qv = qp[qb0 + d] + qp[(size_t)PN + qb0 + d];
            else    qv = (float)qb[qb0 + d];
            a += qv * kv[d * 64 + (lane ^ (d & 31))];
        }
        a *= scale;
        if (CAUSAL && lane > q) a = -__builtin_inff();
        float m = a;
#pragma unroll
        for (int off = 32; off; off >>= 1) m = fmaxf(m, __shfl_xor(m, off, 64));
        float e = (CAUSAL && lane > q) ? 0.f : __expf(a - m);
        float s = e;
#pragma unroll
        for (int off = 32; off; off >>= 1) s += __shfl_xor(s, off, 64);
        sc[ql * 64 + lane] = e / s;
    }
    __syncthreads();

    for (int i = 0; i < 48; ++i) {
        const int idx = t + i * 256;
        const int r = idx / HD, c = idx % HD;
        kv[r * HD + c] = (float)vbuf[(size_t)(t0 + r) * vstride + voff0 + hh * HD + c];
    }
    __syncthreads();

    for (int qi = 0; qi < 4; ++qi) {
        const int ql = wave * 4 + qi;
        const int q = qh * 16 + ql;
        float o0 = 0.f, o1 = 0.f, o2 = 0.f;
#pragma unroll 8
        for (int k = 0; k < 64; ++k) {
            const float p = sc[ql * 64 + k];
            o0 += p * kv[k * HD + lane];
            o1 += p * kv[k * HD + 64 + lane];
            o2 += p * kv[k * HD + 128 + lane];
        }
        bf16* op = out + (size_t)(t0 + q) * D_MODEL + hh * HD;
        op[lane] = (bf16)o0; op[64 + lane] = (bf16)o1; op[128 + lane] = (bf16)o2;
    }
}

// ------- residual + LayerNorm (2 split-K partials, optional slice-out) ----
template<bool SLICE>
__global__ __launch_bounds__(256)
void ln_kernel(const float* __restrict__ a, const float* __restrict__ r,
               const float* __restrict__ r2,
               const float* __restrict__ w, const float* __restrict__ bb,
               float* __restrict__ out, bf16* __restrict__ outb,
               float* __restrict__ out2)
{
    __shared__ float red[8];
    const int tok = blockIdx.x, t = threadIdx.x;
    const int wave = t >> 6, lane = t & 63;
    const float* ap = a + (size_t)tok * D_MODEL;
    const float* rp = r + (size_t)tok * D_MODEL;
    const float* rp2 = r2 + (size_t)tok * D_MODEL;
    float v[6];
    float s = 0.f;
#pragma unroll
    for (int j = 0; j < 6; ++j) {
        const int d = t + j * 256;
        v[j] = ap[d] + rp[d] + rp2[d];
        s += v[j];
    }
#pragma unroll
    for (int off = 32; off; off >>= 1) s += __shfl_xor(s, off, 64);
    if (lane == 0) red[wave] = s;
    __syncthreads();
    const float mu = (red[0] + red[1] + red[2] + red[3]) * (1.f / D_MODEL);
    float s2 = 0.f;
#pragma unroll
    for (int j = 0; j < 6; ++j) { const float d = v[j] - mu; s2 += d * d; }
#pragma unroll
    for (int off = 32; off; off >>= 1) s2 += __shfl_xor(s2, off, 64);
    if (lane == 0) red[4 + wave] = s2;
    __syncthreads();
    const float var = (red[4] + red[5] + red[6] + red[7]) * (1.f / D_MODEL);
    const float inv = rsqrtf(var + EPSF);
    const int bq = tok >> 6, lq = tok & 63;
#pragma unroll
    for (int j = 0; j < 6; ++j) {
        const int d = t + j * 256;
        const float o = (v[j] - mu) * inv * w[d] + bb[d];
        out[(size_t)tok * D_MODEL + d] = o;
        outb[(size_t)tok * D_MODEL + d] = (bf16)o;
        if (SLICE && lq < 63) out2[(size_t)(bq * 63 + lq) * D_MODEL + d] = o;
    }
}

extern "C" void kernel_launch(void* const* d_in, const int* in_sizes, int n_in,
                              void* d_out, int out_size, void* d_ws, size_t ws_size,
                              hipStream_t stream)
{
    (void)in_sizes; (void)n_in; (void)out_size; (void)ws_size;
    const float* x        = (const float*)d_in[0];
    const float* pooler_w = (const float*)d_in[1];
    const float* pooler_b = (const float*)d_in[2];
    const float* pos      = (const float*)d_in[3];
    const float* sa_qkv_w = (const float*)d_in[4];
    const float* sa_qkv_b = (const float*)d_in[5];
    const float* sa_out_w = (const float*)d_in[6];
    const float* sa_out_b = (const float*)d_in[7];
    const float* ca_qkv_w = (const float*)d_in[8];
    const float* ca_qkv_b = (const float*)d_in[9];
    const float* ca_out_w = (const float*)d_in[10];
    const float* ca_out_b = (const float*)d_in[11];
    const float* ff1_w    = (const float*)d_in[12];
    const float* ff1_b    = (const float*)d_in[13];
    const float* ff2_w    = (const float*)d_in[14];
    const float* ff2_b    = (const float*)d_in[15];
    const float* ln1_w    = (const float*)d_in[16];
    const float* ln1_b    = (const float*)d_in[17];
    const float* ln2_w    = (const float*)d_in[18];
    const float* ln2_b    = (const float*)d_in[19];
    const float* ln3_w    = (const float*)d_in[20];
    const float* ln3_b    = (const float*)d_in[21];
    float* outp = (float*)d_out;

    char* ws = (char*)d_ws;
    size_t off = 0;
    auto alloc = [&](size_t bytes) { char* p = ws + off; off += (bytes + 255) & ~(size_t)255; return p; };

    const size_t E_QKV = (size_t)4608 * D_MODEL;
    const size_t E_SQ  = (size_t)D_MODEL * D_MODEL;
    const size_t E_F1  = (size_t)2048 * D_MODEL;
    const int    PN    = NTOK * D_MODEL;           // partial stride (elems)

    // contiguous bf16 weight block (order must match prep cvt boundaries)
    bf16* wb_sa_qkv = (bf16*)alloc(2 * E_QKV * 2);
    bf16* wb_sa_out = (bf16*)alloc(2 * E_SQ * 2);
    bf16* wb_ca_qkv = (bf16*)alloc(2 * E_QKV * 2);
    bf16* wb_ca_out = (bf16*)alloc(2 * E_SQ * 2);
    bf16* wb_ff1    = (bf16*)alloc(2 * E_F1 * 2);
    bf16* wb_ff2    = (bf16*)alloc(2 * E_F1 * 2);
    float* h     = (float*)alloc((size_t)NTOK * D_MODEL * 4);
    bf16*  hb    = (bf16*) alloc((size_t)NTOK * D_MODEL * 2);
    bf16*  memb  = (bf16*) alloc((size_t)NTOK * D_MODEL * 2);
    bf16*  qkvb  = (bf16*) alloc((size_t)NTOK * 4608 * 2);
    float* cq01  = (float*)alloc((size_t)PN * 4 * 2);               // 2 partials
    bf16*  ckv0  = (bf16*) alloc((size_t)NTOK * 3072 * 2);
    bf16*  ckv1  = (bf16*) alloc((size_t)NTOK * 3072 * 2);
    bf16*  attno = (bf16*) alloc((size_t)NTOK * D_MODEL * 2);
    float* proj01= (float*)alloc((size_t)PN * 4 * 2);               // 2 partials
    float* f1p01 = (float*)alloc((size_t)NTOK * 2048 * 4 * 2);      // 2 partials

    float* cq1   = cq01   + (size_t)PN;
    float* proj1 = proj01 + (size_t)PN;
    float* f1p1  = f1p01  + (size_t)NTOK * 2048;

    prep_kernel<<<3072, 256, 0, stream>>>(x, pooler_w, pooler_b, pos, h, hb, memb,
                                          sa_qkv_w, sa_out_w, ca_qkv_w,
                                          ca_out_w, ff1_w, ff2_w, wb_sa_qkv);

    // both layers' cross-attn K/V depend only on memb: one DUAL bf16 dispatch
    gemm8_kernel<2, true, 0><<<16 * 24 * 2, 512, 0, stream>>>(
        memb, wb_ca_qkv + (size_t)1536 * D_MODEL, ca_qkv_b + 1536,
        ckv0, 3072, D_MODEL, 16 * 24,
        memb, wb_ca_qkv + E_QKV + (size_t)1536 * D_MODEL, ca_qkv_b + 4608 + 1536,
        ckv1, 3072);

    for (int i = 0; i < 2; ++i) {
        bf16* ckv = i ? ckv1 : ckv0;

        gemm8_kernel<2, false, 0><<<16 * 36, 512, 0, stream>>>(
            hb, wb_sa_qkv + (size_t)i * E_QKV, sa_qkv_b + (size_t)i * 4608,
            qkvb, 4608, D_MODEL, 0, nullptr, nullptr, nullptr, nullptr, 0);
        attn_kernel<true, false><<<BB * NH * 4, 256, 0, stream>>>(
            qkvb, nullptr, 0, 4608, 0, qkvb, 4608, 1536, qkvb, 4608, 3072, attno);
        gemm8_kernel<0, false, 2><<<16 * 12 * 2, 512, 0, stream>>>(
            attno, wb_sa_out + (size_t)i * E_SQ, sa_out_b + (size_t)i * D_MODEL,
            proj01, D_MODEL, D_MODEL, 0, nullptr, nullptr, nullptr, nullptr, 0);
        ln_kernel<false><<<NTOK, 256, 0, stream>>>(
            h, proj01, proj1, ln1_w + i * D_MODEL, ln1_b + i * D_MODEL, h, hb, nullptr);

        gemm8_kernel<0, false, 2><<<16 * 12 * 2, 512, 0, stream>>>(
            hb, wb_ca_qkv + (size_t)i * E_QKV, ca_qkv_b + (size_t)i * 4608,
            cq01, D_MODEL, D_MODEL, 0, nullptr, nullptr, nullptr, nullptr, 0);
        attn_kernel<false, true><<<BB * NH * 4, 256, 0, stream>>>(
            nullptr, cq01, PN, 1536, 0, ckv, 3072, 0, ckv, 3072, 1536, attno);
        gemm8_kernel<0, false, 2><<<16 * 12 * 2, 512, 0, stream>>>(
            attno, wb_ca_out + (size_t)i * E_SQ, ca_out_b + (size_t)i * D_MODEL,
            proj01, D_MODEL, D_MODEL, 0, nullptr, nullptr, nullptr, nullptr, 0);
        ln_kernel<false><<<NTOK, 256, 0, stream>>>(
            h, proj01, proj1, ln2_w + i * D_MODEL, ln2_b + i * D_MODEL, h, hb, nullptr);

        gemm8_kernel<0, false, 2><<<16 * 16 * 2, 512, 0, stream>>>(
            hb, wb_ff1 + (size_t)i * E_F1, ff1_b + (size_t)i * 2048,
            f1p01, 2048, D_MODEL, 0, nullptr, nullptr, nullptr, nullptr, 0);
        gemm_ff2_kernel<<<16 * 12 * 2, 512, 0, stream>>>(
            f1p01, f1p1, ff2_b + (size_t)i * D_MODEL, proj01,
            wb_ff2 + (size_t)i * E_F1, D_MODEL, 2048);
        if (i == 0)
            ln_kernel<false><<<NTOK, 256, 0, stream>>>(
                h, proj01, proj1, ln3_w, ln3_b, h, hb, nullptr);
        else
            ln_kernel<true><<<NTOK, 256, 0, stream>>>(
                h, proj01, proj1, ln3_w + D_MODEL, ln3_b + D_MODEL, h, hb, outp);
    }
}